// Round 8
// baseline (2161.913 us; speedup 1.0000x reference)
//
#include <hip/hip_runtime.h>
#include <float.h>

#define N_ROWS 65536
#define D_IN   128
#define DH     64
#define K_CB   2048

typedef const __attribute__((address_space(1))) void* gas_p;
typedef __attribute__((address_space(3))) void* las_p;
typedef _Float16 f16x8 __attribute__((ext_vector_type(8)));
typedef float    f32x4 __attribute__((ext_vector_type(4)));

// ---------------- K1: project 128 -> 64, emit 2-plane fp16 split -----------
// v2: 64 rows/block (W staged once per 64 rows, not per 16), Z/emb rows read
// directly as wave-uniform float4 (L1-broadcast), OH zeroing interleaved in 4
// chunks through the FMA loop. LDS = Wl only (35.8KB -> 4 blocks/CU).
// blocks 0..1023: z rows (64/block) + zero matching one_hot rows (512KB NT).
// blocks 1024..1055: embedding rows + e2.
__global__ __launch_bounds__(256) void k_project(
    const float* __restrict__ Z, const float* __restrict__ emb,
    const float* __restrict__ W, const float* __restrict__ b,
    _Float16* __restrict__ zpl,   // [2][N_ROWS][64]
    _Float16* __restrict__ epl,   // [2][K_CB][64]
    float* __restrict__ e2,
    float* __restrict__ outOH) {  // non-null => zero one_hot rows here
  __shared__ __align__(16) float Wl[64 * 140];   // stride 140: limits read conflicts
  int tid = threadIdx.x, lane = tid & 63, g = tid >> 6;
  bool is_z = (int)blockIdx.x < 1024;
  const float* src; _Float16* dst; int n0; size_t plane;
  if (is_z) {
    src = Z;   dst = zpl; n0 = blockIdx.x * 64;          plane = (size_t)N_ROWS * 64;
  } else {
    src = emb; dst = epl; n0 = ((int)blockIdx.x - 1024) * 64; plane = (size_t)K_CB * 64;
  }

#pragma unroll
  for (int i = 0; i < 8; ++i) {
    int idx4 = tid + 256 * i;            // 0..2047 float4s
    int j = idx4 >> 5;
    int d4 = (idx4 & 31) * 4;
    *(float4*)&Wl[j * 140 + d4] = *(const float4*)(W + j * 128 + d4);
  }
  float bj = b[lane];
  __syncthreads();

  // wave g owns rows g*16..g*16+15; lane = output dim j
  const float* zbase = src + (size_t)(n0 + g * 16) * 128;
  f32x4* ohrow = (is_z && outOH) ? (f32x4*)(outOH + (size_t)n0 * K_CB) : nullptr;

  float acc[16];
#pragma unroll
  for (int i = 0; i < 16; ++i) acc[i] = 0.f;

#pragma unroll
  for (int c = 0; c < 4; ++c) {
    // one_hot zero chunk c (128KB of this block's contiguous 512KB region);
    // NT stores stream under the FMA loop, drain only at kernel end.
    if (ohrow) {
      f32x4 zz = (f32x4){0.f, 0.f, 0.f, 0.f};
#pragma unroll
      for (int s2 = 0; s2 < 32; ++s2)
        __builtin_nontemporal_store(zz, ohrow + c * 8192 + tid + 256 * s2);
    }
#pragma unroll
    for (int dd = 0; dd < 8; ++dd) {
      int d4 = c * 32 + dd * 4;
      float4 w4 = *(float4*)&Wl[lane * 140 + d4];
#pragma unroll
      for (int i = 0; i < 16; ++i) {
        float4 z4 = *(const float4*)(zbase + i * 128 + d4);  // wave-uniform (L1)
        acc[i] = fmaf(z4.x, w4.x, fmaf(z4.y, w4.y, fmaf(z4.z, w4.z, fmaf(z4.w, w4.w, acc[i]))));
      }
    }
  }

#pragma unroll
  for (int i = 0; i < 16; ++i) {
    int n = n0 + g * 16 + i;
    float v = acc[i] + bj;
    _Float16 h = (_Float16)v;  float rm = v - (float)h;
    _Float16 m = (_Float16)rm;
    int pos = (((lane >> 3) ^ (n & 7)) << 3) | (lane & 7);   // 16B-chunk swizzle
    size_t base = (size_t)n * 64 + pos;
    dst[base]         = h;
    dst[plane + base] = m;
    if (!is_z) {
      float s = v * v;                   // exact fp32 ||e_||^2
#pragma unroll
      for (int off = 32; off > 0; off >>= 1) s += __shfl_xor(s, off, 64);
      if (lane == 0) e2[n] = s;
    }
  }
}

// ---------------- K2: MFMA score + argmin + fused epilogue -----------------
// (R5 version, unchanged.) 64 z-rows/block. 32 K-tiles of 64 cols, double-
// buffered Es, one barrier per tile (stage t+1 before compute of t). A-frags
// hoisted to registers once. 4 fp16 MFMA passes = fp32-accurate dots.
__global__ __launch_bounds__(256, 3) void k_score(
    const _Float16* __restrict__ zpl,  // [2][N_ROWS][64] swizzled
    const _Float16* __restrict__ epl,  // [2][K_CB][64] swizzled
    const float* __restrict__ e2,      // [2048]
    const float* __restrict__ emb,     // [2048][128]
    float* __restrict__ outQ,
    float* __restrict__ outOH,         // null => fallback (write cidx_g)
    int* __restrict__ cidx_g) {
  __shared__ __align__(16) char U[49152];
  _Float16* Zs  = (_Float16*)U;             // [2][64][64] 16KB
  char*     es0 = U + 16384;                // 16KB
  char*     es1 = U + 32768;                // 16KB

  int tid = threadIdx.x, lane = tid & 63, wid = tid >> 6;
  int quad = lane >> 4, l16 = lane & 15;
  int row0 = blockIdx.x * 64;

  // stage Z tile (2 planes x 8KB) + K-tile 0 -> es0 (2 planes x 8KB)
  for (int q = wid; q < 16; q += 4) {
    int p = q >> 3, within = (q & 7) * 1024;
    const char* g = (const char*)zpl + (size_t)p * ((size_t)N_ROWS * 128)
                  + (size_t)row0 * 128 + within + lane * 16;
    __builtin_amdgcn_global_load_lds((gas_p)g, (las_p)((char*)Zs + p * 8192 + within), 16, 0, 0);
  }
  for (int q = wid; q < 16; q += 4) {
    int p = q >> 3, within = (q & 7) * 1024;
    const char* g = (const char*)epl + (size_t)p * (K_CB * 128) + within + lane * 16;
    __builtin_amdgcn_global_load_lds((gas_p)g, (las_p)(es0 + p * 8192 + within), 16, 0, 0);
  }

  __syncthreads();                     // Zs + tile0 ready

  // ---- A-fragments to registers, once (invariant across all K-tiles) ----
  f16x8 A[2][4][2];
#pragma unroll
  for (int step = 0; step < 2; ++step)
#pragma unroll
    for (int mt = 0; mt < 4; ++mt) {
      int tr = mt * 16 + l16;
      int cph = (step * 4 + quad) ^ (tr & 7);
      const _Float16* pa = Zs + tr * 64 + cph * 8;
      A[step][mt][0] = *(const f16x8*)pa;          // hi
      A[step][mt][1] = *(const f16x8*)(pa + 4096); // mid
    }

  float best[16]; int bidx[16];
#pragma unroll
  for (int s = 0; s < 16; ++s) { best[s] = FLT_MAX; bidx[s] = 0; }

  // ---- 2-phase pipelined tile loop: 32 tiles x 64 cols, 1 barrier/tile ----
  for (int t = 0; t < 32; ++t) {
    const _Float16* esc = (const _Float16*)((t & 1) ? es1 : es0);
    if (t < 31) {                      // stage t+1 FIRST (latency under compute)
      char* esn = (t & 1) ? es0 : es1;
      for (int q = wid; q < 16; q += 4) {
        int p = q >> 3, within = (q & 7) * 1024;
        const char* g = (const char*)epl + (size_t)p * (K_CB * 128)
                      + (size_t)(t + 1) * 8192 + within + lane * 16;
        __builtin_amdgcn_global_load_lds((gas_p)g, (las_p)(esn + p * 8192 + within), 16, 0, 0);
      }
    }
    int col = t * 64 + wid * 16 + l16;
    float ev = e2[col];                // L2-hot; latency hidden under MFMA

    f32x4 accf[4];
#pragma unroll
    for (int mt = 0; mt < 4; ++mt) accf[mt] = (f32x4){0.f, 0.f, 0.f, 0.f};

#pragma unroll
    for (int step = 0; step < 2; ++step) {
      int tc = wid * 16 + l16;
      int cph = (step * 4 + quad) ^ (l16 & 7);
      const _Float16* pb = esc + tc * 64 + cph * 8;
      f16x8 Bh = *(const f16x8*)pb;
      f16x8 Bm = *(const f16x8*)(pb + 4096);
#pragma unroll
      for (int mt = 0; mt < 4; ++mt) {
        f32x4 c = accf[mt];
        c = __builtin_amdgcn_mfma_f32_16x16x32_f16(A[step][mt][1], Bm, c, 0, 0, 0); // mm
        c = __builtin_amdgcn_mfma_f32_16x16x32_f16(A[step][mt][1], Bh, c, 0, 0, 0); // mh
        c = __builtin_amdgcn_mfma_f32_16x16x32_f16(A[step][mt][0], Bm, c, 0, 0, 0); // hm
        c = __builtin_amdgcn_mfma_f32_16x16x32_f16(A[step][mt][0], Bh, c, 0, 0, 0); // hh
        accf[mt] = c;
      }
    }

    // fold into running argmin (strict < + ascending t => earliest index)
#pragma unroll
    for (int mt = 0; mt < 4; ++mt)
#pragma unroll
      for (int r = 0; r < 4; ++r) {
        float s = fmaf(-2.0f, accf[mt][r], ev);
        int slot = mt * 4 + r;
        if (s < best[slot]) { best[slot] = s; bidx[slot] = col; }
      }

    __syncthreads();   // esc readers done; t+1 loads drained -> ready
  }

  // ---- cross-lane reduction: 64 rows x 64 (wave,l16) slots; reuse U ----
  float* redm = (float*)U;                  // [64][64] 16KB
  int*   redi = (int*)(U + 16384);          // [64][64] 16KB
#pragma unroll
  for (int mt = 0; mt < 4; ++mt)
#pragma unroll
    for (int r = 0; r < 4; ++r) {
      int row = mt * 16 + quad * 4 + r;     // C-layout: row = quad*4 + reg
      redm[row * 64 + wid * 16 + l16] = best[mt * 4 + r];
      redi[row * 64 + wid * 16 + l16] = bidx[mt * 4 + r];
    }
  __syncthreads();
  int* cidx = (int*)(U + 32768);
  if (tid < 64) {
    float m = redm[tid * 64]; int mi = redi[tid * 64];
    for (int s = 1; s < 64; ++s) {
      float v = redm[tid * 64 + s]; int vi = redi[tid * 64 + s];
      if (v < m || (v == m && vi < mi)) { m = v; mi = vi; }
    }
    cidx[tid] = mi;
  }
  __syncthreads();

  if (outOH) {
    // zeros were written by k_project (prior kernel on this stream => visible)
    if (tid < 64) outOH[(size_t)(row0 + tid) * K_CB + cidx[tid]] = 1.0f;
  } else {
    if (tid < 64) cidx_g[row0 + tid] = cidx[tid];
  }

  // quantized gather (emb L2-hot); NT stores keep L2 for epl/zpl
#pragma unroll
  for (int i = 0; i < 8; ++i) {
    int idx = tid + 256 * i;           // 0..2047 float4s
    int r = idx >> 5, c = (idx & 31) * 4;
    f32x4 v = *(const f32x4*)(emb + (size_t)cidx[r] * D_IN + c);
    __builtin_nontemporal_store(v, (f32x4*)(outQ + (size_t)(row0 + r) * D_IN + c));
  }
}

// ---------------- K3: fallback epilogue (zero one_hot + scatter) -----------
__global__ void k_epilogue(const int* __restrict__ cidx_g, float* __restrict__ outOH) {
  int tid  = threadIdx.x;
  int row0 = blockIdx.x * 64;
  float4 zz4 = make_float4(0.f, 0.f, 0.f, 0.f);
  for (int r = 0; r < 64; ++r) {
    float4* dst = (float4*)(outOH + (size_t)(row0 + r) * K_CB);
    dst[tid]       = zz4;
    dst[tid + 256] = zz4;
  }
  __syncthreads();
  if (tid < 64) {
    int r = row0 + tid;
    outOH[(size_t)r * K_CB + cidx_g[r]] = 1.0f;
  }
}

extern "C" void kernel_launch(void* const* d_in, const int* in_sizes, int n_in,
                              void* d_out, int out_size, void* d_ws, size_t ws_size,
                              hipStream_t stream) {
  (void)in_sizes; (void)n_in; (void)out_size;
  const float* Z   = (const float*)d_in[0];
  const float* W   = (const float*)d_in[1];
  const float* b   = (const float*)d_in[2];
  const float* emb = (const float*)d_in[3];
  float* outQ  = (float*)d_out;
  float* outOH = (float*)d_out + (size_t)N_ROWS * D_IN;

  // ws layout (bytes): epl 524288 | e2 8192 | (zpl 16777216  OR  cidx 262144)
  char* wsb = (char*)d_ws;
  _Float16* epl = (_Float16*)wsb;
  float*    e2  = (float*)(wsb + 524288);
  const size_t need_primary = 524288 + 8192 + (size_t)2 * N_ROWS * 64 * 2;

  if (ws_size >= need_primary) {
    _Float16* zpl = (_Float16*)(wsb + 532480);
    k_project<<<1056, 256, 0, stream>>>(Z, emb, W, b, zpl, epl, e2, outOH);
    k_score<<<1024, 256, 0, stream>>>(zpl, epl, e2, emb, outQ, outOH, nullptr);
  } else {
    // fallback: z planes live in the (not-yet-needed) one_hot region;
    // k_project must NOT zero it (aliases zpl) -> k_epilogue zeroes later.
    int*      cidx_g = (int*)(wsb + 532480);
    _Float16* zpl    = (_Float16*)outOH;
    k_project<<<1056, 256, 0, stream>>>(Z, emb, W, b, zpl, epl, e2, nullptr);
    k_score<<<1024, 256, 0, stream>>>(zpl, epl, e2, emb, outQ, nullptr, cidx_g);
    k_epilogue<<<1024, 256, 0, stream>>>(cidx_g, outOH);
  }
}

// Round 9
// 664.555 us; speedup vs baseline: 3.2532x; 3.2532x over previous
//
#include <hip/hip_runtime.h>
#include <float.h>

#define N_ROWS 65536
#define D_IN   128
#define DH     64
#define K_CB   2048

typedef const __attribute__((address_space(1))) void* gas_p;
typedef __attribute__((address_space(3))) void* las_p;
typedef _Float16 f16x8 __attribute__((ext_vector_type(8)));
typedef float    f32x4 __attribute__((ext_vector_type(4)));

// ---------------- K1: project 128 -> 64, emit 2-plane fp16 split -----------
// (R5-proven version, unchanged.) z_ = h + m (11+11 mantissa-bit split); rows
// stored [n][64] with a 16B-chunk XOR swizzle: chunk c at c ^ (n&7).
// blocks 0..4095: z rows (16/block) + zero matching one_hot rows (128 KB NT,
// overlapped with compute); blocks 4096..4223: embedding rows + e2.
__global__ __launch_bounds__(256) void k_project(
    const float* __restrict__ Z, const float* __restrict__ emb,
    const float* __restrict__ W, const float* __restrict__ b,
    _Float16* __restrict__ zpl,   // [2][N_ROWS][64]
    _Float16* __restrict__ epl,   // [2][K_CB][64]
    float* __restrict__ e2,
    float* __restrict__ outOH) {  // non-null => zero one_hot rows here
  __shared__ __align__(16) float Wl[64 * 140];   // stride 140: limits read conflicts
  __shared__ __align__(16) float Zl[16 * 128];
  int tid = threadIdx.x;
  const float* src; _Float16* dst; int n0; bool do_e2; size_t plane;
  if ((int)blockIdx.x < 4096) {
    src = Z;   dst = zpl; n0 = blockIdx.x * 16;          do_e2 = false; plane = (size_t)N_ROWS * 64;
  } else {
    src = emb; dst = epl; n0 = (blockIdx.x - 4096) * 16; do_e2 = true;  plane = (size_t)K_CB * 64;
  }

#pragma unroll
  for (int i = 0; i < 8; ++i) {
    int idx4 = tid + 256 * i;            // 0..2047 float4s
    int j = idx4 >> 5;
    int d4 = (idx4 & 31) * 4;
    *(float4*)&Wl[j * 140 + d4] = *(const float4*)(W + j * 128 + d4);
  }
#pragma unroll
  for (int i = 0; i < 2; ++i) {
    int idx4 = tid + 256 * i;            // 0..511 float4s
    int r = idx4 >> 5;
    int d4 = (idx4 & 31) * 4;
    *(float4*)&Zl[r * 128 + d4] = *(const float4*)(src + (size_t)(n0 + r) * 128 + d4);
  }
  int j = tid & 63, g = tid >> 6;        // j = output dim, g = wave -> 4 rows
  float bj = b[j];
  __syncthreads();

  // one_hot zeroing AFTER the barrier: streams under the FMA loop, drains only
  // at kernel end (no barrier waits on these store acks).
  if (outOH && (int)blockIdx.x < 4096) {
    f32x4 zz4 = (f32x4){0.f, 0.f, 0.f, 0.f};
    f32x4* dz = (f32x4*)(outOH + (size_t)n0 * K_CB);   // 16 rows x 2048 = 8192 float4
#pragma unroll
    for (int i = 0; i < 32; ++i)
      __builtin_nontemporal_store(zz4, dz + tid + 256 * i);
  }

  float acc[4] = {0.f, 0.f, 0.f, 0.f};
  for (int d4 = 0; d4 < 128; d4 += 4) {
    float4 w4 = *(float4*)&Wl[j * 140 + d4];
#pragma unroll
    for (int i = 0; i < 4; ++i) {
      float4 z4 = *(float4*)&Zl[(g * 4 + i) * 128 + d4]; // wave-uniform broadcast
      acc[i] = fmaf(z4.x, w4.x, fmaf(z4.y, w4.y, fmaf(z4.z, w4.z, fmaf(z4.w, w4.w, acc[i]))));
    }
  }
#pragma unroll
  for (int i = 0; i < 4; ++i) {
    int n = n0 + g * 4 + i;
    float v = acc[i] + bj;
    _Float16 h = (_Float16)v;  float rm = v - (float)h;
    _Float16 m = (_Float16)rm;
    int pos = (((j >> 3) ^ (n & 7)) << 3) | (j & 7);   // 16B-chunk swizzle
    size_t base = (size_t)n * 64 + pos;
    dst[base]         = h;
    dst[plane + base] = m;
    if (do_e2) {
      float s = v * v;                   // exact fp32 ||e_||^2
#pragma unroll
      for (int off = 32; off > 0; off >>= 1) s += __shfl_xor(s, off, 64);
      if (j == 0) e2[n] = s;
    }
  }
}

// ---------------- K2: MFMA score + argmin + fused epilogue -----------------
// v3: 128 z-rows/block, 512 blocks => 2 blocks/CU, ALL co-resident (zero
// sequential rounds). Per tile the MFMA work doubles (64/wave) so staging
// latency is covered; epl L2 re-reads halve (512->256 MB aggregate).
// Group-0 rows (0..63): A-frags hoisted to registers (64 VGPR, as R5).
// Group-1 rows (64..127): A-frags re-read from LDS per tile (2-way max
// conflicts; keeps VGPR ~190, no spill). Numerics identical to R5.
__global__ __launch_bounds__(256, 2) void k_score(
    const _Float16* __restrict__ zpl,  // [2][N_ROWS][64] swizzled
    const _Float16* __restrict__ epl,  // [2][K_CB][64] swizzled
    const float* __restrict__ e2,      // [2048]
    const float* __restrict__ emb,     // [2048][128]
    float* __restrict__ outQ,
    float* __restrict__ outOH,         // null => fallback (write cidx_g)
    int* __restrict__ cidx_g) {
  __shared__ __align__(16) char U[65536];
  _Float16* Zs  = (_Float16*)U;             // [2pl][128][64] 32KB (live all loop)
  char*     es0 = U + 32768;                // [2pl][64][64] 16KB
  char*     es1 = U + 49152;                // 16KB
  __shared__ int cidxs[128];

  int tid = threadIdx.x, lane = tid & 63, wid = tid >> 6;
  int quad = lane >> 4, l16 = lane & 15;
  int row0 = blockIdx.x * 128;

  // stage Z rows (2 planes x 16KB) + K-tile 0 -> es0 (2 planes x 8KB)
  for (int q = wid; q < 32; q += 4) {
    int p = q >> 4, within = (q & 15) * 1024;
    const char* g = (const char*)zpl + (size_t)p * ((size_t)N_ROWS * 128)
                  + (size_t)row0 * 128 + within + lane * 16;
    __builtin_amdgcn_global_load_lds((gas_p)g, (las_p)((char*)Zs + p * 16384 + within), 16, 0, 0);
  }
  for (int q = wid; q < 16; q += 4) {
    int p = q >> 3, within = (q & 7) * 1024;
    const char* g = (const char*)epl + (size_t)p * (K_CB * 128) + within + lane * 16;
    __builtin_amdgcn_global_load_lds((gas_p)g, (las_p)(es0 + p * 8192 + within), 16, 0, 0);
  }

  __syncthreads();                     // Zs + tile0 ready

  // ---- group-0 A-fragments to registers (plane stride now 8192 elems) ----
  f16x8 A[2][4][2];
#pragma unroll
  for (int step = 0; step < 2; ++step)
#pragma unroll
    for (int mt = 0; mt < 4; ++mt) {
      int tr = mt * 16 + l16;
      int cph = (step * 4 + quad) ^ (tr & 7);
      const _Float16* pa = Zs + tr * 64 + cph * 8;
      A[step][mt][0] = *(const f16x8*)pa;          // hi
      A[step][mt][1] = *(const f16x8*)(pa + 8192); // mid
    }

  float best[32]; int bidx[32];
#pragma unroll
  for (int s = 0; s < 32; ++s) { best[s] = FLT_MAX; bidx[s] = 0; }

  // ---- 2-phase pipelined tile loop: 32 tiles x 64 cols, 1 barrier/tile ----
  for (int t = 0; t < 32; ++t) {
    const _Float16* esc = (const _Float16*)((t & 1) ? es1 : es0);
    if (t < 31) {                      // stage t+1 FIRST (latency under compute)
      char* esn = (t & 1) ? es0 : es1;
      for (int q = wid; q < 16; q += 4) {
        int p = q >> 3, within = (q & 7) * 1024;
        const char* g = (const char*)epl + (size_t)p * (K_CB * 128)
                      + (size_t)(t + 1) * 8192 + within + lane * 16;
        __builtin_amdgcn_global_load_lds((gas_p)g, (las_p)(esn + p * 8192 + within), 16, 0, 0);
      }
    }
    int col = t * 64 + wid * 16 + l16;
    float ev = e2[col];                // L2-hot; latency hidden under MFMA

    f32x4 acc0[4], acc1[4];
#pragma unroll
    for (int mt = 0; mt < 4; ++mt) {
      acc0[mt] = (f32x4){0.f, 0.f, 0.f, 0.f};
      acc1[mt] = (f32x4){0.f, 0.f, 0.f, 0.f};
    }

#pragma unroll
    for (int step = 0; step < 2; ++step) {
      int tc = wid * 16 + l16;
      int cph = (step * 4 + quad) ^ (l16 & 7);
      const _Float16* pb = esc + tc * 64 + cph * 8;
      f16x8 Bh = *(const f16x8*)pb;
      f16x8 Bm = *(const f16x8*)(pb + 4096);
      // group 0: A from registers
#pragma unroll
      for (int mt = 0; mt < 4; ++mt) {
        f32x4 c = acc0[mt];
        c = __builtin_amdgcn_mfma_f32_16x16x32_f16(A[step][mt][1], Bm, c, 0, 0, 0); // mm
        c = __builtin_amdgcn_mfma_f32_16x16x32_f16(A[step][mt][1], Bh, c, 0, 0, 0); // mh
        c = __builtin_amdgcn_mfma_f32_16x16x32_f16(A[step][mt][0], Bm, c, 0, 0, 0); // hm
        c = __builtin_amdgcn_mfma_f32_16x16x32_f16(A[step][mt][0], Bh, c, 0, 0, 0); // hh
        acc0[mt] = c;
      }
      // group 1: A from LDS (rows 64..127; (64+x)&7 == x&7 -> same swizzle)
#pragma unroll
      for (int mt = 0; mt < 4; ++mt) {
        int tr = 64 + mt * 16 + l16;
        int cph1 = (step * 4 + quad) ^ (tr & 7);
        const _Float16* pa = Zs + tr * 64 + cph1 * 8;
        f16x8 Ah = *(const f16x8*)pa;
        f16x8 Am = *(const f16x8*)(pa + 8192);
        f32x4 c = acc1[mt];
        c = __builtin_amdgcn_mfma_f32_16x16x32_f16(Am, Bm, c, 0, 0, 0); // mm
        c = __builtin_amdgcn_mfma_f32_16x16x32_f16(Am, Bh, c, 0, 0, 0); // mh
        c = __builtin_amdgcn_mfma_f32_16x16x32_f16(Ah, Bm, c, 0, 0, 0); // hm
        c = __builtin_amdgcn_mfma_f32_16x16x32_f16(Ah, Bh, c, 0, 0, 0); // hh
        acc1[mt] = c;
      }
    }

    // fold into running argmin (strict < + ascending t => earliest index)
#pragma unroll
    for (int mt = 0; mt < 4; ++mt)
#pragma unroll
      for (int r = 0; r < 4; ++r) {
        float s0 = fmaf(-2.0f, acc0[mt][r], ev);
        int slot = mt * 4 + r;
        if (s0 < best[slot]) { best[slot] = s0; bidx[slot] = col; }
        float s1 = fmaf(-2.0f, acc1[mt][r], ev);
        if (s1 < best[16 + slot]) { best[16 + slot] = s1; bidx[16 + slot] = col; }
      }

    __syncthreads();   // esc readers done; t+1 loads drained -> ready
  }

  // ---- cross-lane reduction: 128 rows x 64 (wave,l16) slots; reuse U ----
  float* redm = (float*)U;                  // [128][64] 32KB (Zs dead)
  int*   redi = (int*)(U + 32768);          // [128][64] 32KB (es dead)
#pragma unroll
  for (int grp = 0; grp < 2; ++grp)
#pragma unroll
    for (int mt = 0; mt < 4; ++mt)
#pragma unroll
      for (int r = 0; r < 4; ++r) {
        int row = grp * 64 + mt * 16 + quad * 4 + r;  // C-layout: row = quad*4 + reg
        redm[row * 64 + wid * 16 + l16] = best[grp * 16 + mt * 4 + r];
        redi[row * 64 + wid * 16 + l16] = bidx[grp * 16 + mt * 4 + r];
      }
  __syncthreads();
  if (tid < 128) {
    float m = redm[tid * 64]; int mi = redi[tid * 64];
    for (int s = 1; s < 64; ++s) {
      float v = redm[tid * 64 + s]; int vi = redi[tid * 64 + s];
      if (v < m || (v == m && vi < mi)) { m = v; mi = vi; }
    }
    cidxs[tid] = mi;
  }
  __syncthreads();

  if (outOH) {
    // zeros were written by k_project (prior kernel on this stream => visible)
    if (tid < 128) outOH[(size_t)(row0 + tid) * K_CB + cidxs[tid]] = 1.0f;
  } else {
    if (tid < 128) cidx_g[row0 + tid] = cidxs[tid];
  }

  // quantized gather (emb L2-hot); NT stores keep L2 for epl/zpl
#pragma unroll
  for (int i = 0; i < 16; ++i) {
    int idx = tid + 256 * i;           // 0..4095 float4s (128 rows x 32)
    int r = idx >> 5, c = (idx & 31) * 4;
    f32x4 v = *(const f32x4*)(emb + (size_t)cidxs[r] * D_IN + c);
    __builtin_nontemporal_store(v, (f32x4*)(outQ + (size_t)(row0 + r) * D_IN + c));
  }
}

// ---------------- K3: fallback epilogue (zero one_hot + scatter) -----------
__global__ void k_epilogue(const int* __restrict__ cidx_g, float* __restrict__ outOH) {
  int tid  = threadIdx.x;
  int row0 = blockIdx.x * 64;
  float4 zz4 = make_float4(0.f, 0.f, 0.f, 0.f);
  for (int r = 0; r < 64; ++r) {
    float4* dst = (float4*)(outOH + (size_t)(row0 + r) * K_CB);
    dst[tid]       = zz4;
    dst[tid + 256] = zz4;
  }
  __syncthreads();
  if (tid < 64) {
    int r = row0 + tid;
    outOH[(size_t)r * K_CB + cidx_g[r]] = 1.0f;
  }
}

extern "C" void kernel_launch(void* const* d_in, const int* in_sizes, int n_in,
                              void* d_out, int out_size, void* d_ws, size_t ws_size,
                              hipStream_t stream) {
  (void)in_sizes; (void)n_in; (void)out_size;
  const float* Z   = (const float*)d_in[0];
  const float* W   = (const float*)d_in[1];
  const float* b   = (const float*)d_in[2];
  const float* emb = (const float*)d_in[3];
  float* outQ  = (float*)d_out;
  float* outOH = (float*)d_out + (size_t)N_ROWS * D_IN;

  // ws layout (bytes): epl 524288 | e2 8192 | (zpl 16777216  OR  cidx 262144)
  char* wsb = (char*)d_ws;
  _Float16* epl = (_Float16*)wsb;
  float*    e2  = (float*)(wsb + 524288);
  const size_t need_primary = 524288 + 8192 + (size_t)2 * N_ROWS * 64 * 2;

  if (ws_size >= need_primary) {
    _Float16* zpl = (_Float16*)(wsb + 532480);
    k_project<<<4224, 256, 0, stream>>>(Z, emb, W, b, zpl, epl, e2, outOH);
    k_score<<<512, 256, 0, stream>>>(zpl, epl, e2, emb, outQ, outOH, nullptr);
  } else {
    // fallback: z planes live in the (not-yet-needed) one_hot region;
    // k_project must NOT zero it (aliases zpl) -> k_epilogue zeroes later.
    int*      cidx_g = (int*)(wsb + 532480);
    _Float16* zpl    = (_Float16*)outOH;
    k_project<<<4224, 256, 0, stream>>>(Z, emb, W, b, zpl, epl, e2, nullptr);
    k_score<<<512, 256, 0, stream>>>(zpl, epl, e2, emb, outQ, nullptr, cidx_g);
    k_epilogue<<<1024, 256, 0, stream>>>(cidx_g, outOH);
  }
}